// Round 17
// baseline (138.406 us; speedup 1.0000x reference)
//
#include <hip/hip_runtime.h>

#define NN      10000
#define IN_DIM  128
#define E_DIM   32
#define NH      4
#define DH      32
#define HD      128   // NH*DH
#define NE_     640000
#define OUT_DIM 32
#define SCAN_T  1024
#define CHUNK   10    // SCAN_T*CHUNK >= NN
#define NTILES  (NN / 16)        // 625 node-tiles
#define NTASKS  (NTILES * 3)     // x 3 col-groups (Q, K, P)
#define QKVP_BLKS  469           // ceil(NTASKS/4)
#define EE_BLKS    (NE_ / 256)   // 2500
#define HIST_BLKS  (NE_ / 256)   // 2500

typedef __attribute__((ext_vector_type(8))) short bf16x8;
typedef __attribute__((ext_vector_type(4))) float f32x4;
typedef __attribute__((ext_vector_type(2))) unsigned u32x2;

static __device__ __forceinline__ unsigned short f32_to_bf16_rne(float f) {
    unsigned u = __float_as_uint(f);
    return (unsigned short)((u + 0x7fffu + ((u >> 16) & 1u)) >> 16);
}
static __device__ __forceinline__ float bf16_bits_to_f32(unsigned short h) {
    return __uint_as_float(((unsigned)h) << 16);
}
static __device__ __forceinline__ float blo(unsigned u) { return __uint_as_float(u << 16); }
static __device__ __forceinline__ float bhi(unsigned u) { return __uint_as_float(u & 0xffff0000u); }
static __device__ __forceinline__ unsigned short f32_to_f16b(float f) {
    _Float16 h = (_Float16)f;
    return *reinterpret_cast<unsigned short*>(&h);
}
static __device__ __forceinline__ float f16b_to_f32(unsigned short u) {
    _Float16 h = *reinterpret_cast<_Float16*>(&u);
    return (float)h;
}

// ---------------------------------------------------------------------------
// Kernel A (prep + hist, block-range dispatch; all parts independent):
//  blocks [0,24):   wfrag -- hi/lo A-fragments of [Wq|Wk|Wp], Wp inline
//  blocks [24,26):  wet   -- hi/lo A-fragments of We
//  block  26:       bp[flat] = sum_d bv[h*32+d]*Wo[..o],  flat = o*4+h
//  blocks [27,...): hist_rank -- deg histogram + per-edge rank (rank stored NT:
//                   read exactly once by mm, keep L2 for the atomics)
// ---------------------------------------------------------------------------
__global__ __launch_bounds__(256) void prep_kernel(
    const float* __restrict__ Wq, const float* __restrict__ Wk,
    const float* __restrict__ Wv, const float* __restrict__ Wo,
    const float* __restrict__ bv, const float* __restrict__ We,
    const int*   __restrict__ ei,
    unsigned short* __restrict__ wfh, unsigned short* __restrict__ wfl,
    unsigned short* __restrict__ wefh, unsigned short* __restrict__ wefl,
    float* __restrict__ bp,
    int* __restrict__ deg, int* __restrict__ rank)
{
    const int blk = blockIdx.x;
    const int t = threadIdx.x;

    if (blk < 24) {                         // ---- wfrag (6144 threads) ----
        const int tid = blk * 256 + t;      // (tt*4+s)*64 + l
        const int l = tid & 63;
        const int ts = tid >> 6;
        const int s = ts & 3, tt = ts >> 2; // tt 0..23
        const int col = (tt & 7) * 16 + (l & 15);
        if (tt < 16) {
            const float* __restrict__ W = (tt < 8) ? Wq : Wk;
            #pragma unroll
            for (int j = 0; j < 8; ++j) {
                const int k = s * 32 + (l >> 4) * 8 + j;
                const float w = W[k * HD + col];
                const unsigned short hi = f32_to_bf16_rne(w);
                wfh[tid * 8 + j] = hi;
                wfl[tid * 8 + j] = f32_to_bf16_rne(w - bf16_bits_to_f32(hi));
            }
        } else {                            // Wp inline
            const int h = col & 3, oo = col >> 2;
            #pragma unroll
            for (int j = 0; j < 8; ++j) {
                const int k = s * 32 + (l >> 4) * 8 + j;
                float acc = 0.f;
                #pragma unroll
                for (int d2 = 0; d2 < DH; ++d2)
                    acc = fmaf(Wv[k * HD + h * DH + d2],
                               Wo[(h * DH + d2) * OUT_DIM + oo], acc);
                const unsigned short hi = f32_to_bf16_rne(acc);
                wfh[tid * 8 + j] = hi;
                wfl[tid * 8 + j] = f32_to_bf16_rne(acc - bf16_bits_to_f32(hi));
            }
        }
    } else if (blk < 26) {                  // ---- wet (512 threads) ----
        const int tid = (blk - 24) * 256 + t;
        const int l = tid & 63, tt = tid >> 6;
        #pragma unroll
        for (int j = 0; j < 8; ++j) {
            const int k = (l >> 4) * 8 + j;
            const int d = tt * 16 + (l & 15);
            const float w = We[k * HD + d];
            const unsigned short hi = f32_to_bf16_rne(w);
            wefh[tid * 8 + j] = hi;
            wefl[tid * 8 + j] = f32_to_bf16_rne(w - bf16_bits_to_f32(hi));
        }
    } else if (blk == 26) {                 // ---- bp ----
        if (t < HD) {
            const int h = t & 3, oo = t >> 2;
            float b = 0.f;
            #pragma unroll
            for (int d2 = 0; d2 < DH; ++d2)
                b = fmaf(bv[h * DH + d2], Wo[(h * DH + d2) * OUT_DIM + oo], b);
            bp[t] = b;
        }
    } else {                                // ---- hist_rank ----
        const int e = (blk - 27) * 256 + t;
        const int r = atomicAdd(&deg[ei[e]], 1);
        __builtin_nontemporal_store(r, &rank[e]);
    }
}

// ---------------------------------------------------------------------------
// Kernel B: exclusive scan of deg -> off (shfl-based, 2 barriers)
// ---------------------------------------------------------------------------
__global__ __launch_bounds__(SCAN_T) void scan_kernel(
    const int* __restrict__ deg, int* __restrict__ off)
{
    __shared__ int wsum[16];
    const int t = threadIdx.x;
    const int lane = t & 63, w = t >> 6;
    const int base = t * CHUNK;
    int v[CHUNK];
    int sum = 0;
    #pragma unroll
    for (int i = 0; i < CHUNK; ++i) {
        const int idx = base + i;
        v[i] = (idx < NN) ? deg[idx] : 0;
        sum += v[i];
    }
    int incl = sum;
    #pragma unroll
    for (int dlt = 1; dlt < 64; dlt <<= 1) {
        const int nb = __shfl_up(incl, dlt, 64);
        if (lane >= dlt) incl += nb;
    }
    if (lane == 63) wsum[w] = incl;
    __syncthreads();
    if (w == 0) {
        const int val = (lane < 16) ? wsum[lane] : 0;
        int wi = val;
        #pragma unroll
        for (int dlt = 1; dlt < 16; dlt <<= 1) {
            const int nb = __shfl_up(wi, dlt, 64);
            if (lane >= dlt) wi += nb;
        }
        if (lane < 16) wsum[lane] = wi - val;   // exclusive wave prefix
    }
    __syncthreads();
    int run = wsum[w] + (incl - sum);
    #pragma unroll
    for (int i = 0; i < CHUNK; ++i) {
        const int idx = base + i;
        if (idx < NN) { off[idx] = run; run += v[i]; }
    }
}

// ---------------------------------------------------------------------------
// Kernel C (mm, block-range dispatch -- R16 structure + NT cache hints):
//  blocks [0,QKVP_BLKS):  node GEMM [Q|K|PT] = x @ [Wq|Wk|Wp]. x loads NT
//    (read-once stream). KPTb/Q stores stay cached (fg re-reads them).
//  blocks [QKVP_BLKS,..): ee via split-We MFMA. ea loads NT (read-once 82MB
//    stream -- the L2 polluter that evicts pay lines mid-merge); pay store NT.
//    Goal: pay's 64B lines (8 stores each) stay in L2 until fully merged ->
//    WRITE_SIZE amplification 6x -> ~2x.
//  All fragments/accumulators are named scalars (R6: arrays got LDS-promoted).
// ---------------------------------------------------------------------------
__global__ __launch_bounds__(256) void mm_kernel(
    const float* __restrict__ x,
    const unsigned short* __restrict__ wfh, const unsigned short* __restrict__ wfl,
    const float* __restrict__ bq, const float* __restrict__ bk,
    const float* __restrict__ bp,
    float* __restrict__ Q, unsigned short* __restrict__ KPTb,
    const float* __restrict__ ea,
    const unsigned short* __restrict__ wefh, const unsigned short* __restrict__ wefl,
    const float* __restrict__ be,
    const int* __restrict__ ei,
    const int* __restrict__ off, const int* __restrict__ rank,
    u32x2* __restrict__ pay)
{
    const int lane = threadIdx.x & 63;
    const int wave = threadIdx.x >> 6;

    if (blockIdx.x < QKVP_BLKS) {
        // ------------------- qkvp GEMM -------------------
        const int task = blockIdx.x * 4 + wave;
        if (task >= NTASKS) return;
        const int nt = task / 3, cg = task - nt * 3;
        const int node = nt * 16 + (lane & 15);
        const int kc = lane >> 4;          // 0..3

        bf16x8 xh0, xl0, xh1, xl1, xh2, xl2, xh3, xl3;
#define SPL(VH, VL, I, VAL) { \
    const unsigned short hh = f32_to_bf16_rne(VAL); \
    VH[I] = (short)hh; VL[I] = (short)f32_to_bf16_rne((VAL) - bf16_bits_to_f32(hh)); }
#define LOAD_X(S, VH, VL) { \
    const f32x4* xr = reinterpret_cast<const f32x4*>( \
        x + (size_t)node * IN_DIM + (S) * 32 + kc * 8); \
    const f32x4 a0 = __builtin_nontemporal_load(xr); \
    const f32x4 a1 = __builtin_nontemporal_load(xr + 1); \
    SPL(VH, VL, 0, a0[0]) SPL(VH, VL, 1, a0[1]) SPL(VH, VL, 2, a0[2]) SPL(VH, VL, 3, a0[3]) \
    SPL(VH, VL, 4, a1[0]) SPL(VH, VL, 5, a1[1]) SPL(VH, VL, 6, a1[2]) SPL(VH, VL, 7, a1[3]) }
        LOAD_X(0, xh0, xl0) LOAD_X(1, xh1, xl1) LOAD_X(2, xh2, xl2) LOAD_X(3, xh3, xl3)
#undef LOAD_X
#undef SPL

        const float* __restrict__ bb = (cg == 0) ? bq : (cg == 1) ? bk : bp;

#define KSTEP(S, FB, FB2, XH, XL) { \
    const bf16x8 wh = *reinterpret_cast<const bf16x8*>((FB)  + (S) * 64 * 8); \
    const bf16x8 wl = *reinterpret_cast<const bf16x8*>((FB2) + (S) * 64 * 8); \
    acc = __builtin_amdgcn_mfma_f32_16x16x32_bf16(wh, XH, acc, 0, 0, 0); \
    acc = __builtin_amdgcn_mfma_f32_16x16x32_bf16(wh, XL, acc, 0, 0, 0); \
    acc = __builtin_amdgcn_mfma_f32_16x16x32_bf16(wl, XH, acc, 0, 0, 0); }

#define TILE(TLOC) { \
    const unsigned short* fb  = wfh + ((((cg * 8 + TLOC) * 4) * 64 + lane) << 3); \
    const unsigned short* fb2 = wfl + ((((cg * 8 + TLOC) * 4) * 64 + lane) << 3); \
    const float4 b4 = *reinterpret_cast<const float4*>(bb + (TLOC) * 16 + (kc << 2)); \
    f32x4 acc = {b4.x, b4.y, b4.z, b4.w}; \
    KSTEP(0, fb, fb2, xh0, xl0) KSTEP(1, fb, fb2, xh1, xl1) \
    KSTEP(2, fb, fb2, xh2, xl2) KSTEP(3, fb, fb2, xh3, xl3) \
    const int j0 = (TLOC) * 16 + (kc << 2); \
    if (cg == 0) { \
        *reinterpret_cast<float4*>(Q + (size_t)node * HD + j0) = \
            make_float4(acc[0], acc[1], acc[2], acc[3]); \
    } else { \
        unsigned short* dp = KPTb + (size_t)node * 256 + j0 * 2 + ((cg == 1) ? 0 : 4); \
        *reinterpret_cast<ushort4*>(dp) = make_ushort4( \
            f32_to_bf16_rne(acc[0]), f32_to_bf16_rne(acc[1]), \
            f32_to_bf16_rne(acc[2]), f32_to_bf16_rne(acc[3])); \
    } }

        TILE(0) TILE(1) TILE(2) TILE(3) TILE(4) TILE(5) TILE(6) TILE(7)
#undef TILE
#undef KSTEP
        return;
    }

    // ------------------- ee + 8B CSR payload scatter -------------------
    const int base = (blockIdx.x - QKVP_BLKS) * 256 + wave * 64;  // 64 edges/wave

    const int src  = ei[base + lane];
    const int dstn = ei[NE_ + base + lane];
    const int pos  = off[src] + __builtin_nontemporal_load(&rank[base + lane]);

    const int erow = lane & 15;
    const int kc = lane >> 4;          // k-chunk 0..3
    bf16x8 ah0, ah1, ah2, ah3;
#define LOAD_A(AT, VAR) { \
    const f32x4* ar = reinterpret_cast<const f32x4*>( \
        ea + (size_t)(base + AT * 16 + erow) * E_DIM + kc * 8); \
    const f32x4 a0 = __builtin_nontemporal_load(ar); \
    const f32x4 a1 = __builtin_nontemporal_load(ar + 1); \
    VAR[0] = (short)f32_to_bf16_rne(a0[0]); VAR[1] = (short)f32_to_bf16_rne(a0[1]); \
    VAR[2] = (short)f32_to_bf16_rne(a0[2]); VAR[3] = (short)f32_to_bf16_rne(a0[3]); \
    VAR[4] = (short)f32_to_bf16_rne(a1[0]); VAR[5] = (short)f32_to_bf16_rne(a1[1]); \
    VAR[6] = (short)f32_to_bf16_rne(a1[2]); VAR[7] = (short)f32_to_bf16_rne(a1[3]); }
    LOAD_A(0, ah0) LOAD_A(1, ah1) LOAD_A(2, ah2) LOAD_A(3, ah3)
#undef LOAD_A

    float p00 = 0.f, p01 = 0.f, p02 = 0.f, p03 = 0.f;
    float p10 = 0.f, p11 = 0.f, p12 = 0.f, p13 = 0.f;
    float p20 = 0.f, p21 = 0.f, p22 = 0.f, p23 = 0.f;
    float p30 = 0.f, p31 = 0.f, p32 = 0.f, p33 = 0.f;

#define AT_BODY(AT, H, WHI, WLO, BE4) { \
    f32x4 acc = {BE4.x, BE4.y, BE4.z, BE4.w}; \
    acc = __builtin_amdgcn_mfma_f32_16x16x32_bf16(WLO, ah##AT, acc, 0, 0, 0); \
    acc = __builtin_amdgcn_mfma_f32_16x16x32_bf16(WHI, ah##AT, acc, 0, 0, 0); \
    p##AT##H = fmaf(acc[0], acc[0], fmaf(acc[1], acc[1], \
               fmaf(acc[2], acc[2], fmaf(acc[3], acc[3], p##AT##H)))); }

#define TILE(T, H) { \
    const bf16x8 whi = *reinterpret_cast<const bf16x8*>(wefh + ((T * 64 + lane) << 3)); \
    const bf16x8 wlo = *reinterpret_cast<const bf16x8*>(wefl + ((T * 64 + lane) << 3)); \
    const float4 be4 = *reinterpret_cast<const float4*>(be + T * 16 + ((lane >> 4) << 2)); \
    AT_BODY(0, H, whi, wlo, be4) AT_BODY(1, H, whi, wlo, be4) \
    AT_BODY(2, H, whi, wlo, be4) AT_BODY(3, H, whi, wlo, be4) }

    TILE(0, 0) TILE(1, 0) TILE(2, 1) TILE(3, 1)
    TILE(4, 2) TILE(5, 2) TILE(6, 3) TILE(7, 3)
#undef TILE
#undef AT_BODY

#define RED(AT, H) \
    float r##AT##H = p##AT##H; \
    r##AT##H += __shfl_xor(r##AT##H, 16, 64); \
    r##AT##H += __shfl_xor(r##AT##H, 32, 64);
    RED(0, 0) RED(0, 1) RED(0, 2) RED(0, 3)
    RED(1, 0) RED(1, 1) RED(1, 2) RED(1, 3)
    RED(2, 0) RED(2, 1) RED(2, 2) RED(2, 3)
    RED(3, 0) RED(3, 1) RED(3, 2) RED(3, 3)
#undef RED

    const int at4 = lane >> 4;
#define SEL(H) ((at4 & 2) ? ((at4 & 1) ? r3##H : r2##H) : ((at4 & 1) ? r1##H : r0##H))
    const float w0 = SEL(0), w1 = SEL(1), w2 = SEL(2), w3 = SEL(3);
#undef SEL

    const unsigned short d0 = f32_to_f16b(w0 - w3);
    const unsigned short d1 = f32_to_f16b(w1 - w3);
    const unsigned short d2 = f32_to_f16b(w2 - w3);
    u32x2 pv;
    pv[0] = (unsigned)dstn | ((unsigned)d0 << 16);
    pv[1] = (unsigned)d1 | ((unsigned)d2 << 16);
    __builtin_nontemporal_store(pv, &pay[pos]);
}

// ---------------------------------------------------------------------------
// Kernel D: fused score+softmax+aggregate, CSR order, 16 lanes per edge.
//   (R16 structure; pay loads NT -- read-once, keep L2 for KPTb which is the
//   reuse-heavy gather target; out store NT -- written once, never re-read)
// ---------------------------------------------------------------------------
__global__ __launch_bounds__(256) void fused_gather_kernel(
    const int* __restrict__ off, const int* __restrict__ deg,
    const u32x2* __restrict__ pay,
    const float* __restrict__ Q, const unsigned short* __restrict__ KPTb,
    const float* __restrict__ bo, float* __restrict__ out)
{
    __shared__ float red[16][OUT_DIM];
    const int n = blockIdx.x;
    const int d = deg[n];
    const int start = off[n];
    const int tid = threadIdx.x;
    const int g = tid >> 4;          // group 0..15
    const int o16 = tid & 15;        // lane in group
    const int h = o16 >> 2;
    const float scale = 0.17677669529663687f;  // 1/sqrt(32)

    const float* __restrict__ qrow = Q + (size_t)n * HD + o16 * 8;
    const float4 qa = *reinterpret_cast<const float4*>(qrow);
    const float4 qb = *reinterpret_cast<const float4*>(qrow + 4);

    float acc0 = 0.f, acc1 = 0.f;

    // prologue: pc, pn payloads; uc KPT row for pc
    u32x2 pc = {0u, 0u};
    u32x2 pn = {0u, 0u};
    if (g < d)      pc = __builtin_nontemporal_load(&pay[start + g]);
    if (g + 16 < d) pn = __builtin_nontemporal_load(&pay[start + g + 16]);
    uint4 uc0, uc1;
    {
        const unsigned short* __restrict__ kp =
            KPTb + (size_t)(pc[0] & 0xffffu) * 256 + o16 * 16;
        uc0 = *reinterpret_cast<const uint4*>(kp);
        uc1 = *reinterpret_cast<const uint4*>(kp + 8);
    }

    for (int i = g; i < d; i += 16) {
        // prefetch payload for i+32
        u32x2 pn2 = {0u, 0u};
        if (i + 32 < d) pn2 = __builtin_nontemporal_load(&pay[start + i + 32]);
        // prefetch KPT row for i+16 (pn already resident)
        uint4 un0 = make_uint4(0, 0, 0, 0), un1 = make_uint4(0, 0, 0, 0);
        if (i + 16 < d) {
            const unsigned short* __restrict__ kp =
                KPTb + (size_t)(pn[0] & 0xffffu) * 256 + o16 * 16;
            un0 = *reinterpret_cast<const uint4*>(kp);
            un1 = *reinterpret_cast<const uint4*>(kp + 8);
        }

        // compute with pc / uc
        float p =           qa.x * blo(uc0.x);
        p = fmaf(qa.y, bhi(uc0.x), p);
        p = fmaf(qa.z, blo(uc0.y), p);
        p = fmaf(qa.w, bhi(uc0.y), p);
        p = fmaf(qb.x, blo(uc1.x), p);
        p = fmaf(qb.y, bhi(uc1.x), p);
        p = fmaf(qb.z, blo(uc1.y), p);
        p = fmaf(qb.w, bhi(uc1.y), p);
        p += __shfl_xor(p, 1, 64);
        p += __shfl_xor(p, 2, 64);           // qk_h in each 4-lane cluster
        const float b  = __shfl_xor(p, 4, 64);
        const float e0 = (h & 1) ? b : p;
        const float e1 = (h & 1) ? p : b;
        const float o0 = __shfl_xor(e0, 8, 64);
        const float o1 = __shfl_xor(e1, 8, 64);
        const float qk0 = (h & 2) ? o0 : e0;
        const float qk1 = (h & 2) ? o1 : e1;
        const float qk2 = (h & 2) ? e0 : o0;
        const float qk3 = (h & 2) ? e1 : o1;

        const float ee0 = f16b_to_f32((unsigned short)(pc[0] >> 16));
        const float ee1 = f16b_to_f32((unsigned short)(pc[1] & 0xffffu));
        const float ee2 = f16b_to_f32((unsigned short)(pc[1] >> 16));
        const float s0 = (qk0 + ee0) * scale;
        const float s1 = (qk1 + ee1) * scale;
        const float s2 = (qk2 + ee2) * scale;
        const float s3 = qk3 * scale;
        const float mx = fmaxf(fmaxf(s0, s1), fmaxf(s2, s3));
        const float a0 = __expf(s0 - mx), a1 = __expf(s1 - mx);
        const float a2 = __expf(s2 - mx), a3 = __expf(s3 - mx);
        const float inv = 1.f / (a0 + a1 + a2 + a3);

        float c0 =          a0 * blo(uc0.z);
        c0 = fmaf(a1, bhi(uc0.z), c0);
        c0 = fmaf(a2, blo(uc0.w), c0);
        c0 = fmaf(a3, bhi(uc0.w), c0);
        float c1 =          a0 * blo(uc1.z);
        c1 = fmaf(a1, bhi(uc1.z), c1);
        c1 = fmaf(a2, blo(uc1.w), c1);
        c1 = fmaf(a3, bhi(uc1.w), c1);
        acc0 = fmaf(c0, inv, acc0);
        acc1 = fmaf(c1, inv, acc1);

        pc = pn; pn = pn2; uc0 = un0; uc1 = un1;
    }
    red[g][o16 * 2]     = acc0;
    red[g][o16 * 2 + 1] = acc1;
    __syncthreads();
    if (tid < 32) {
        float s = 0.f;
        #pragma unroll
        for (int gg = 0; gg < 16; ++gg) s += red[gg][tid];
        const float r = (d > 0) ? (s / (float)d + bo[tid]) : 0.f;
        __builtin_nontemporal_store(r, &out[(size_t)n * OUT_DIM + tid]);
    }
}

extern "C" void kernel_launch(void* const* d_in, const int* in_sizes, int n_in,
                              void* d_out, int out_size, void* d_ws, size_t ws_size,
                              hipStream_t stream)
{
    const float* x   = (const float*)d_in[0];
    const int*   ei  = (const int*)  d_in[1];
    const float* ea  = (const float*)d_in[2];
    const float* Wq  = (const float*)d_in[3];
    const float* bq  = (const float*)d_in[4];
    const float* Wk  = (const float*)d_in[5];
    const float* bk  = (const float*)d_in[6];
    const float* Wv  = (const float*)d_in[7];
    const float* bv  = (const float*)d_in[8];
    const float* We  = (const float*)d_in[9];
    const float* be  = (const float*)d_in[10];
    const float* Wo  = (const float*)d_in[11];
    const float* bo  = (const float*)d_in[12];
    float* out = (float*)d_out;

    // workspace layout (16B-aligned chunks)
    float*  Q    = (float*)d_ws;                          // NN*HD f32        (5.12MB)
    u32x2*  pay  = (u32x2*)(Q + (size_t)NN * HD);         // NE_ uint2        (5.12MB)
    unsigned short* KPTb = (unsigned short*)(pay + NE_);  // NN*256 bf16      (5.12MB)
    float*  bp   = (float*)(KPTb + (size_t)NN * 256);     // HD f32
    unsigned short* wefh = (unsigned short*)(bp + HD);    // 4096
    unsigned short* wefl = wefh + 8 * 64 * 8;             // 4096
    unsigned short* wfh  = wefl + 8 * 64 * 8;             // 24*4*64*8 = 49152
    unsigned short* wfl  = wfh + 24 * 4 * 64 * 8;         // 49152
    int* rank = (int*)(wfl + 24 * 4 * 64 * 8);            // NE_
    int* deg  = rank + NE_;                               // NN
    int* off  = deg + NN;                                 // NN

    hipMemsetAsync(deg, 0, NN * sizeof(int), stream);

    prep_kernel<<<27 + HIST_BLKS, 256, 0, stream>>>(Wq, Wk, Wv, Wo, bv, We, ei,
                                                    wfh, wfl, wefh, wefl, bp,
                                                    deg, rank);
    scan_kernel<<<1, SCAN_T, 0, stream>>>(deg, off);
    mm_kernel<<<QKVP_BLKS + EE_BLKS, 256, 0, stream>>>(x, wfh, wfl, bq, bk, bp,
                                                       Q, KPTb, ea, wefh, wefl,
                                                       be, ei, off, rank, pay);
    fused_gather_kernel<<<NN, 256, 0, stream>>>(off, deg, pay, Q, KPTb, bo, out);
}

// Round 18
// 121.206 us; speedup vs baseline: 1.1419x; 1.1419x over previous
//
#include <hip/hip_runtime.h>

#define NN      10000
#define IN_DIM  128
#define E_DIM   32
#define NH      4
#define DH      32
#define HD      128   // NH*DH
#define NE_     640000
#define OUT_DIM 32
#define SCAN_T  1024
#define CHUNK   10    // SCAN_T*CHUNK >= NN
#define NTILES  (NN / 16)        // 625 node-tiles
#define NTASKS  (NTILES * 3)     // x 3 col-groups (Q, K, P)
#define QKVP_BLKS  469           // ceil(NTASKS/4)
#define EE_BLKS    (NE_ / 256)   // 2500
#define HIST_BLKS  (NE_ / 256)   // 2500

typedef __attribute__((ext_vector_type(8))) short bf16x8;
typedef __attribute__((ext_vector_type(4))) float f32x4;

static __device__ __forceinline__ unsigned short f32_to_bf16_rne(float f) {
    unsigned u = __float_as_uint(f);
    return (unsigned short)((u + 0x7fffu + ((u >> 16) & 1u)) >> 16);
}
static __device__ __forceinline__ float bf16_bits_to_f32(unsigned short h) {
    return __uint_as_float(((unsigned)h) << 16);
}
static __device__ __forceinline__ float blo(unsigned u) { return __uint_as_float(u << 16); }
static __device__ __forceinline__ float bhi(unsigned u) { return __uint_as_float(u & 0xffff0000u); }
static __device__ __forceinline__ unsigned short f32_to_f16b(float f) {
    _Float16 h = (_Float16)f;
    return *reinterpret_cast<unsigned short*>(&h);
}
static __device__ __forceinline__ float f16b_to_f32(unsigned short u) {
    _Float16 h = *reinterpret_cast<_Float16*>(&u);
    return (float)h;
}

// ---------------------------------------------------------------------------
// Kernel A (prep + hist, block-range dispatch; all parts independent):
//  blocks [0,24):   wfrag -- hi/lo A-fragments of [Wq|Wk|Wp], Wp inline
//  blocks [24,26):  wet   -- hi/lo A-fragments of We
//  block  26:       bp[flat] = sum_d bv[h*32+d]*Wo[..o],  flat = o*4+h
//  blocks [27,...): hist_rank -- deg histogram + per-edge rank
// ---------------------------------------------------------------------------
__global__ __launch_bounds__(256) void prep_kernel(
    const float* __restrict__ Wq, const float* __restrict__ Wk,
    const float* __restrict__ Wv, const float* __restrict__ Wo,
    const float* __restrict__ bv, const float* __restrict__ We,
    const int*   __restrict__ ei,
    unsigned short* __restrict__ wfh, unsigned short* __restrict__ wfl,
    unsigned short* __restrict__ wefh, unsigned short* __restrict__ wefl,
    float* __restrict__ bp,
    int* __restrict__ deg, int* __restrict__ rank)
{
    const int blk = blockIdx.x;
    const int t = threadIdx.x;

    if (blk < 24) {                         // ---- wfrag (6144 threads) ----
        const int tid = blk * 256 + t;      // (tt*4+s)*64 + l
        const int l = tid & 63;
        const int ts = tid >> 6;
        const int s = ts & 3, tt = ts >> 2; // tt 0..23
        const int col = (tt & 7) * 16 + (l & 15);
        if (tt < 16) {
            const float* __restrict__ W = (tt < 8) ? Wq : Wk;
            #pragma unroll
            for (int j = 0; j < 8; ++j) {
                const int k = s * 32 + (l >> 4) * 8 + j;
                const float w = W[k * HD + col];
                const unsigned short hi = f32_to_bf16_rne(w);
                wfh[tid * 8 + j] = hi;
                wfl[tid * 8 + j] = f32_to_bf16_rne(w - bf16_bits_to_f32(hi));
            }
        } else {                            // Wp inline
            const int h = col & 3, oo = col >> 2;
            #pragma unroll
            for (int j = 0; j < 8; ++j) {
                const int k = s * 32 + (l >> 4) * 8 + j;
                float acc = 0.f;
                #pragma unroll
                for (int d2 = 0; d2 < DH; ++d2)
                    acc = fmaf(Wv[k * HD + h * DH + d2],
                               Wo[(h * DH + d2) * OUT_DIM + oo], acc);
                const unsigned short hi = f32_to_bf16_rne(acc);
                wfh[tid * 8 + j] = hi;
                wfl[tid * 8 + j] = f32_to_bf16_rne(acc - bf16_bits_to_f32(hi));
            }
        }
    } else if (blk < 26) {                  // ---- wet (512 threads) ----
        const int tid = (blk - 24) * 256 + t;
        const int l = tid & 63, tt = tid >> 6;
        #pragma unroll
        for (int j = 0; j < 8; ++j) {
            const int k = (l >> 4) * 8 + j;
            const int d = tt * 16 + (l & 15);
            const float w = We[k * HD + d];
            const unsigned short hi = f32_to_bf16_rne(w);
            wefh[tid * 8 + j] = hi;
            wefl[tid * 8 + j] = f32_to_bf16_rne(w - bf16_bits_to_f32(hi));
        }
    } else if (blk == 26) {                 // ---- bp ----
        if (t < HD) {
            const int h = t & 3, oo = t >> 2;
            float b = 0.f;
            #pragma unroll
            for (int d2 = 0; d2 < DH; ++d2)
                b = fmaf(bv[h * DH + d2], Wo[(h * DH + d2) * OUT_DIM + oo], b);
            bp[t] = b;
        }
    } else {                                // ---- hist_rank ----
        const int e = (blk - 27) * 256 + t;
        rank[e] = atomicAdd(&deg[ei[e]], 1);
    }
}

// ---------------------------------------------------------------------------
// Kernel B: exclusive scan of deg -> off (shfl-based, 2 barriers)
// ---------------------------------------------------------------------------
__global__ __launch_bounds__(SCAN_T) void scan_kernel(
    const int* __restrict__ deg, int* __restrict__ off)
{
    __shared__ int wsum[16];
    const int t = threadIdx.x;
    const int lane = t & 63, w = t >> 6;
    const int base = t * CHUNK;
    int v[CHUNK];
    int sum = 0;
    #pragma unroll
    for (int i = 0; i < CHUNK; ++i) {
        const int idx = base + i;
        v[i] = (idx < NN) ? deg[idx] : 0;
        sum += v[i];
    }
    int incl = sum;
    #pragma unroll
    for (int dlt = 1; dlt < 64; dlt <<= 1) {
        const int nb = __shfl_up(incl, dlt, 64);
        if (lane >= dlt) incl += nb;
    }
    if (lane == 63) wsum[w] = incl;
    __syncthreads();
    if (w == 0) {
        const int val = (lane < 16) ? wsum[lane] : 0;
        int wi = val;
        #pragma unroll
        for (int dlt = 1; dlt < 16; dlt <<= 1) {
            const int nb = __shfl_up(wi, dlt, 64);
            if (lane >= dlt) wi += nb;
        }
        if (lane < 16) wsum[lane] = wi - val;   // exclusive wave prefix
    }
    __syncthreads();
    int run = wsum[w] + (incl - sum);
    #pragma unroll
    for (int i = 0; i < CHUNK; ++i) {
        const int idx = base + i;
        if (idx < NN) { off[idx] = run; run += v[i]; }
    }
}

// ---------------------------------------------------------------------------
// Kernel C (mm, block-range dispatch -- exact R16 structure, the proven best;
//  R17's NT cache hints REGRESSED: FETCH/WRITE both rose -- ea stream and pay
//  merges were benefiting from L2 residency):
//  blocks [0,QKVP_BLKS):  node GEMM [Q|K|PT] = x @ [Wq|Wk|Wp] (+bias via MFMA
//    C-init). K/PT interleaved in KPTb rows (512B).
//  blocks [QKVP_BLKS,..): ee via split-We MFMA (be via C-init); 8B payload
//    scatter pay[off[src]+rank[e]] = {dst | f16(ee0-ee3)<<16,
//    f16(ee1-ee3) | f16(ee2-ee3)<<16}.
//  All fragments/accumulators are named scalars (R6: arrays got LDS-promoted).
// ---------------------------------------------------------------------------
__global__ __launch_bounds__(256) void mm_kernel(
    const float* __restrict__ x,
    const unsigned short* __restrict__ wfh, const unsigned short* __restrict__ wfl,
    const float* __restrict__ bq, const float* __restrict__ bk,
    const float* __restrict__ bp,
    float* __restrict__ Q, unsigned short* __restrict__ KPTb,
    const float* __restrict__ ea,
    const unsigned short* __restrict__ wefh, const unsigned short* __restrict__ wefl,
    const float* __restrict__ be,
    const int* __restrict__ ei,
    const int* __restrict__ off, const int* __restrict__ rank,
    uint2* __restrict__ pay)
{
    const int lane = threadIdx.x & 63;
    const int wave = threadIdx.x >> 6;

    if (blockIdx.x < QKVP_BLKS) {
        // ------------------- qkvp GEMM -------------------
        const int task = blockIdx.x * 4 + wave;
        if (task >= NTASKS) return;
        const int nt = task / 3, cg = task - nt * 3;
        const int node = nt * 16 + (lane & 15);
        const int kc = lane >> 4;          // 0..3

        bf16x8 xh0, xl0, xh1, xl1, xh2, xl2, xh3, xl3;
#define SPL(VH, VL, I, VAL) { \
    const unsigned short hh = f32_to_bf16_rne(VAL); \
    VH[I] = (short)hh; VL[I] = (short)f32_to_bf16_rne((VAL) - bf16_bits_to_f32(hh)); }
#define LOAD_X(S, VH, VL) { \
    const float* xr = x + (size_t)node * IN_DIM + (S) * 32 + kc * 8; \
    const float4 a0 = *reinterpret_cast<const float4*>(xr); \
    const float4 a1 = *reinterpret_cast<const float4*>(xr + 4); \
    SPL(VH, VL, 0, a0.x) SPL(VH, VL, 1, a0.y) SPL(VH, VL, 2, a0.z) SPL(VH, VL, 3, a0.w) \
    SPL(VH, VL, 4, a1.x) SPL(VH, VL, 5, a1.y) SPL(VH, VL, 6, a1.z) SPL(VH, VL, 7, a1.w) }
        LOAD_X(0, xh0, xl0) LOAD_X(1, xh1, xl1) LOAD_X(2, xh2, xl2) LOAD_X(3, xh3, xl3)
#undef LOAD_X
#undef SPL

        const float* __restrict__ bb = (cg == 0) ? bq : (cg == 1) ? bk : bp;

#define KSTEP(S, FB, FB2, XH, XL) { \
    const bf16x8 wh = *reinterpret_cast<const bf16x8*>((FB)  + (S) * 64 * 8); \
    const bf16x8 wl = *reinterpret_cast<const bf16x8*>((FB2) + (S) * 64 * 8); \
    acc = __builtin_amdgcn_mfma_f32_16x16x32_bf16(wh, XH, acc, 0, 0, 0); \
    acc = __builtin_amdgcn_mfma_f32_16x16x32_bf16(wh, XL, acc, 0, 0, 0); \
    acc = __builtin_amdgcn_mfma_f32_16x16x32_bf16(wl, XH, acc, 0, 0, 0); }

#define TILE(TLOC) { \
    const unsigned short* fb  = wfh + ((((cg * 8 + TLOC) * 4) * 64 + lane) << 3); \
    const unsigned short* fb2 = wfl + ((((cg * 8 + TLOC) * 4) * 64 + lane) << 3); \
    const float4 b4 = *reinterpret_cast<const float4*>(bb + (TLOC) * 16 + (kc << 2)); \
    f32x4 acc = {b4.x, b4.y, b4.z, b4.w}; \
    KSTEP(0, fb, fb2, xh0, xl0) KSTEP(1, fb, fb2, xh1, xl1) \
    KSTEP(2, fb, fb2, xh2, xl2) KSTEP(3, fb, fb2, xh3, xl3) \
    const int j0 = (TLOC) * 16 + (kc << 2); \
    if (cg == 0) { \
        *reinterpret_cast<float4*>(Q + (size_t)node * HD + j0) = \
            make_float4(acc[0], acc[1], acc[2], acc[3]); \
    } else { \
        unsigned short* dp = KPTb + (size_t)node * 256 + j0 * 2 + ((cg == 1) ? 0 : 4); \
        *reinterpret_cast<ushort4*>(dp) = make_ushort4( \
            f32_to_bf16_rne(acc[0]), f32_to_bf16_rne(acc[1]), \
            f32_to_bf16_rne(acc[2]), f32_to_bf16_rne(acc[3])); \
    } }

        TILE(0) TILE(1) TILE(2) TILE(3) TILE(4) TILE(5) TILE(6) TILE(7)
#undef TILE
#undef KSTEP
        return;
    }

    // ------------------- ee + 8B CSR payload scatter -------------------
    const int base = (blockIdx.x - QKVP_BLKS) * 256 + wave * 64;  // 64 edges/wave

    const int src  = ei[base + lane];
    const int dstn = ei[NE_ + base + lane];
    const int pos  = off[src] + rank[base + lane];

    const int erow = lane & 15;
    const int kc = lane >> 4;          // k-chunk 0..3
    bf16x8 ah0, ah1, ah2, ah3;
#define LOAD_A(AT, VAR) { \
    const float* ar = ea + (size_t)(base + AT * 16 + erow) * E_DIM + kc * 8; \
    const float4 a0 = *reinterpret_cast<const float4*>(ar); \
    const float4 a1 = *reinterpret_cast<const float4*>(ar + 4); \
    VAR[0] = (short)f32_to_bf16_rne(a0.x); VAR[1] = (short)f32_to_bf16_rne(a0.y); \
    VAR[2] = (short)f32_to_bf16_rne(a0.z); VAR[3] = (short)f32_to_bf16_rne(a0.w); \
    VAR[4] = (short)f32_to_bf16_rne(a1.x); VAR[5] = (short)f32_to_bf16_rne(a1.y); \
    VAR[6] = (short)f32_to_bf16_rne(a1.z); VAR[7] = (short)f32_to_bf16_rne(a1.w); }
    LOAD_A(0, ah0) LOAD_A(1, ah1) LOAD_A(2, ah2) LOAD_A(3, ah3)
#undef LOAD_A

    float p00 = 0.f, p01 = 0.f, p02 = 0.f, p03 = 0.f;
    float p10 = 0.f, p11 = 0.f, p12 = 0.f, p13 = 0.f;
    float p20 = 0.f, p21 = 0.f, p22 = 0.f, p23 = 0.f;
    float p30 = 0.f, p31 = 0.f, p32 = 0.f, p33 = 0.f;

#define AT_BODY(AT, H, WHI, WLO, BE4) { \
    f32x4 acc = {BE4.x, BE4.y, BE4.z, BE4.w}; \
    acc = __builtin_amdgcn_mfma_f32_16x16x32_bf16(WLO, ah##AT, acc, 0, 0, 0); \
    acc = __builtin_amdgcn_mfma_f32_16x16x32_bf16(WHI, ah##AT, acc, 0, 0, 0); \
    p##AT##H = fmaf(acc[0], acc[0], fmaf(acc[1], acc[1], \
               fmaf(acc[2], acc[2], fmaf(acc[3], acc[3], p##AT##H)))); }

#define TILE(T, H) { \
    const bf16x8 whi = *reinterpret_cast<const bf16x8*>(wefh + ((T * 64 + lane) << 3)); \
    const bf16x8 wlo = *reinterpret_cast<const bf16x8*>(wefl + ((T * 64 + lane) << 3)); \
    const float4 be4 = *reinterpret_cast<const float4*>(be + T * 16 + ((lane >> 4) << 2)); \
    AT_BODY(0, H, whi, wlo, be4) AT_BODY(1, H, whi, wlo, be4) \
    AT_BODY(2, H, whi, wlo, be4) AT_BODY(3, H, whi, wlo, be4) }

    TILE(0, 0) TILE(1, 0) TILE(2, 1) TILE(3, 1)
    TILE(4, 2) TILE(5, 2) TILE(6, 3) TILE(7, 3)
#undef TILE
#undef AT_BODY

#define RED(AT, H) \
    float r##AT##H = p##AT##H; \
    r##AT##H += __shfl_xor(r##AT##H, 16, 64); \
    r##AT##H += __shfl_xor(r##AT##H, 32, 64);
    RED(0, 0) RED(0, 1) RED(0, 2) RED(0, 3)
    RED(1, 0) RED(1, 1) RED(1, 2) RED(1, 3)
    RED(2, 0) RED(2, 1) RED(2, 2) RED(2, 3)
    RED(3, 0) RED(3, 1) RED(3, 2) RED(3, 3)
#undef RED

    const int at4 = lane >> 4;
#define SEL(H) ((at4 & 2) ? ((at4 & 1) ? r3##H : r2##H) : ((at4 & 1) ? r1##H : r0##H))
    const float w0 = SEL(0), w1 = SEL(1), w2 = SEL(2), w3 = SEL(3);
#undef SEL

    const unsigned short d0 = f32_to_f16b(w0 - w3);
    const unsigned short d1 = f32_to_f16b(w1 - w3);
    const unsigned short d2 = f32_to_f16b(w2 - w3);
    pay[pos] = make_uint2((unsigned)dstn | ((unsigned)d0 << 16),
                          (unsigned)d1 | ((unsigned)d2 << 16));
}

// ---------------------------------------------------------------------------
// Kernel D: fused score+softmax+aggregate, CSR order, 16 lanes per edge.
//   (exact R16 structure; payload 8B: dst 14b + 3 fp16 ee-deltas)
//   block = node n, 16 groups of 16 lanes; 4 edges per wave-instruction.
//   Deep software pipeline: payload 2 iters ahead, KPT row 1 iter ahead.
// ---------------------------------------------------------------------------
__global__ __launch_bounds__(256) void fused_gather_kernel(
    const int* __restrict__ off, const int* __restrict__ deg,
    const uint2* __restrict__ pay,
    const float* __restrict__ Q, const unsigned short* __restrict__ KPTb,
    const float* __restrict__ bo, float* __restrict__ out)
{
    __shared__ float red[16][OUT_DIM];
    const int n = blockIdx.x;
    const int d = deg[n];
    const int start = off[n];
    const int tid = threadIdx.x;
    const int g = tid >> 4;          // group 0..15
    const int o16 = tid & 15;        // lane in group
    const int h = o16 >> 2;
    const float scale = 0.17677669529663687f;  // 1/sqrt(32)

    const float* __restrict__ qrow = Q + (size_t)n * HD + o16 * 8;
    const float4 qa = *reinterpret_cast<const float4*>(qrow);
    const float4 qb = *reinterpret_cast<const float4*>(qrow + 4);

    float acc0 = 0.f, acc1 = 0.f;

    // prologue: pc, pn payloads; uc KPT row for pc
    uint2 pc = make_uint2(0u, 0u);
    uint2 pn = make_uint2(0u, 0u);
    if (g < d)      pc = pay[start + g];
    if (g + 16 < d) pn = pay[start + g + 16];
    uint4 uc0, uc1;
    {
        const unsigned short* __restrict__ kp =
            KPTb + (size_t)(pc.x & 0xffffu) * 256 + o16 * 16;
        uc0 = *reinterpret_cast<const uint4*>(kp);
        uc1 = *reinterpret_cast<const uint4*>(kp + 8);
    }

    for (int i = g; i < d; i += 16) {
        // prefetch payload for i+32
        uint2 pn2 = make_uint2(0u, 0u);
        if (i + 32 < d) pn2 = pay[start + i + 32];
        // prefetch KPT row for i+16 (pn already resident)
        uint4 un0 = make_uint4(0, 0, 0, 0), un1 = make_uint4(0, 0, 0, 0);
        if (i + 16 < d) {
            const unsigned short* __restrict__ kp =
                KPTb + (size_t)(pn.x & 0xffffu) * 256 + o16 * 16;
            un0 = *reinterpret_cast<const uint4*>(kp);
            un1 = *reinterpret_cast<const uint4*>(kp + 8);
        }

        // compute with pc / uc
        float p =           qa.x * blo(uc0.x);
        p = fmaf(qa.y, bhi(uc0.x), p);
        p = fmaf(qa.z, blo(uc0.y), p);
        p = fmaf(qa.w, bhi(uc0.y), p);
        p = fmaf(qb.x, blo(uc1.x), p);
        p = fmaf(qb.y, bhi(uc1.x), p);
        p = fmaf(qb.z, blo(uc1.y), p);
        p = fmaf(qb.w, bhi(uc1.y), p);
        p += __shfl_xor(p, 1, 64);
        p += __shfl_xor(p, 2, 64);           // qk_h in each 4-lane cluster
        const float b  = __shfl_xor(p, 4, 64);
        const float e0 = (h & 1) ? b : p;
        const float e1 = (h & 1) ? p : b;
        const float o0 = __shfl_xor(e0, 8, 64);
        const float o1 = __shfl_xor(e1, 8, 64);
        const float qk0 = (h & 2) ? o0 : e0;
        const float qk1 = (h & 2) ? o1 : e1;
        const float qk2 = (h & 2) ? e0 : o0;
        const float qk3 = (h & 2) ? e1 : o1;

        const float ee0 = f16b_to_f32((unsigned short)(pc.x >> 16));
        const float ee1 = f16b_to_f32((unsigned short)(pc.y & 0xffffu));
        const float ee2 = f16b_to_f32((unsigned short)(pc.y >> 16));
        const float s0 = (qk0 + ee0) * scale;
        const float s1 = (qk1 + ee1) * scale;
        const float s2 = (qk2 + ee2) * scale;
        const float s3 = qk3 * scale;
        const float mx = fmaxf(fmaxf(s0, s1), fmaxf(s2, s3));
        const float a0 = __expf(s0 - mx), a1 = __expf(s1 - mx);
        const float a2 = __expf(s2 - mx), a3 = __expf(s3 - mx);
        const float inv = 1.f / (a0 + a1 + a2 + a3);

        float c0 =          a0 * blo(uc0.z);
        c0 = fmaf(a1, bhi(uc0.z), c0);
        c0 = fmaf(a2, blo(uc0.w), c0);
        c0 = fmaf(a3, bhi(uc0.w), c0);
        float c1 =          a0 * blo(uc1.z);
        c1 = fmaf(a1, bhi(uc1.z), c1);
        c1 = fmaf(a2, blo(uc1.w), c1);
        c1 = fmaf(a3, bhi(uc1.w), c1);
        acc0 = fmaf(c0, inv, acc0);
        acc1 = fmaf(c1, inv, acc1);

        pc = pn; pn = pn2; uc0 = un0; uc1 = un1;
    }
    red[g][o16 * 2]     = acc0;
    red[g][o16 * 2 + 1] = acc1;
    __syncthreads();
    if (tid < 32) {
        float s = 0.f;
        #pragma unroll
        for (int gg = 0; gg < 16; ++gg) s += red[gg][tid];
        out[(size_t)n * OUT_DIM + tid] = (d > 0) ? (s / (float)d + bo[tid]) : 0.f;
    }
}

extern "C" void kernel_launch(void* const* d_in, const int* in_sizes, int n_in,
                              void* d_out, int out_size, void* d_ws, size_t ws_size,
                              hipStream_t stream)
{
    const float* x   = (const float*)d_in[0];
    const int*   ei  = (const int*)  d_in[1];
    const float* ea  = (const float*)d_in[2];
    const float* Wq  = (const float*)d_in[3];
    const float* bq  = (const float*)d_in[4];
    const float* Wk  = (const float*)d_in[5];
    const float* bk  = (const float*)d_in[6];
    const float* Wv  = (const float*)d_in[7];
    const float* bv  = (const float*)d_in[8];
    const float* We  = (const float*)d_in[9];
    const float* be  = (const float*)d_in[10];
    const float* Wo  = (const float*)d_in[11];
    const float* bo  = (const float*)d_in[12];
    float* out = (float*)d_out;

    // workspace layout (16B-aligned chunks)
    float*  Q    = (float*)d_ws;                          // NN*HD f32        (5.12MB)
    uint2*  pay  = (uint2*)(Q + (size_t)NN * HD);         // NE_ uint2        (5.12MB)
    unsigned short* KPTb = (unsigned short*)(pay + NE_);  // NN*256 bf16      (5.12MB)
    float*  bp   = (float*)(KPTb + (size_t)NN * 256);     // HD f32
    unsigned short* wefh = (unsigned short*)(bp + HD);    // 4096
    unsigned short* wefl = wefh + 8 * 64 * 8;             // 4096
    unsigned short* wfh  = wefl + 8 * 64 * 8;             // 24*4*64*8 = 49152
    unsigned short* wfl  = wfh + 24 * 4 * 64 * 8;         // 49152
    int* rank = (int*)(wfl + 24 * 4 * 64 * 8);            // NE_
    int* deg  = rank + NE_;                               // NN
    int* off  = deg + NN;                                 // NN

    hipMemsetAsync(deg, 0, NN * sizeof(int), stream);

    prep_kernel<<<27 + HIST_BLKS, 256, 0, stream>>>(Wq, Wk, Wv, Wo, bv, We, ei,
                                                    wfh, wfl, wefh, wefl, bp,
                                                    deg, rank);
    scan_kernel<<<1, SCAN_T, 0, stream>>>(deg, off);
    mm_kernel<<<QKVP_BLKS + EE_BLKS, 256, 0, stream>>>(x, wfh, wfl, bq, bk, bp,
                                                       Q, KPTb, ea, wefh, wefl,
                                                       be, ei, off, rank, pay);
    fused_gather_kernel<<<NN, 256, 0, stream>>>(off, deg, pay, Q, KPTb, bo, out);
}